// Round 8
// baseline (210.218 us; speedup 1.0000x reference)
//
#include <hip/hip_runtime.h>

#define N_NODES 50000
#define DIM 128
#define NH 4
#define DH 32
#define NE 800000
#define SCALEF 0.17677669529663688f   // 1/sqrt(32)

typedef _Float16 half_t;
typedef __attribute__((ext_vector_type(2))) _Float16 half2_t;
typedef __attribute__((ext_vector_type(4))) _Float16 half4_t;
typedef __attribute__((ext_vector_type(8))) _Float16 half8_t;
typedef __attribute__((ext_vector_type(4))) float f32x4;
typedef unsigned short u16;
typedef unsigned int u32;

#define HIST_NB 391   // ceil(NE/8/256)
#define SCAT_NB 391   // ceil(NE/8/256)
#define NB_SCAN 49    // ceil(N_NODES/1024)

// ---------------- prep: weights->fp16 (blocks 0..31) + degree histogram (blocks 32..) ----------
__global__ __launch_bounds__(256)
void prep_kernel(const float* __restrict__ w0, const float* __restrict__ w1,
                 const float* __restrict__ w2, const float* __restrict__ w3,
                 half_t* __restrict__ o0, half_t* __restrict__ o1,
                 half_t* __restrict__ o2, half_t* __restrict__ o3,
                 const int* __restrict__ tgt, int* __restrict__ deg)
{
    if (blockIdx.x < 32) {
        const float* src; half_t* dst;
        switch (blockIdx.x >> 3) {
            case 0: src = w0; dst = o0; break;
            case 1: src = w1; dst = o1; break;
            case 2: src = w2; dst = o2; break;
            default: src = w3; dst = o3; break;
        }
        const int i = ((blockIdx.x & 7) * 256 + threadIdx.x) * 8;   // 16384 elems per weight
        const float4 a = *(const float4*)(src + i);
        const float4 b = *(const float4*)(src + i + 4);
        half8_t o;
        o[0] = (_Float16)a.x; o[1] = (_Float16)a.y; o[2] = (_Float16)a.z; o[3] = (_Float16)a.w;
        o[4] = (_Float16)b.x; o[5] = (_Float16)b.y; o[6] = (_Float16)b.z; o[7] = (_Float16)b.w;
        *(half8_t*)(dst + i) = o;
    } else {
        const int i = ((blockIdx.x - 32) * 256 + threadIdx.x) * 8;
        if (i >= NE) return;
        const int4 t4a = *(const int4*)(tgt + i);
        const int4 t4b = *(const int4*)(tgt + i + 4);
        atomicAdd(&deg[t4a.x], 1); atomicAdd(&deg[t4a.y], 1);
        atomicAdd(&deg[t4a.z], 1); atomicAdd(&deg[t4a.w], 1);
        atomicAdd(&deg[t4b.x], 1); atomicAdd(&deg[t4b.y], 1);
        atomicAdd(&deg[t4b.z], 1); atomicAdd(&deg[t4b.w], 1);
    }
}

// ---------------- hierarchical scan: block sums -> scan sums -> block scan (+CUR init) -------
__global__ __launch_bounds__(256)
void block_sums(const int* __restrict__ deg, int* __restrict__ bsum, int n)
{
    __shared__ int acc4[4];
    const int b0 = blockIdx.x * 1024;
    int sum = 0;
    for (int i = threadIdx.x; i < 1024; i += 256) {
        const int g = b0 + i;
        sum += (g < n) ? deg[g] : 0;
    }
    #pragma unroll
    for (int w = 1; w < 64; w <<= 1) sum += __shfl_xor(sum, w);
    if ((threadIdx.x & 63) == 0) acc4[threadIdx.x >> 6] = sum;
    __syncthreads();
    if (threadIdx.x == 0) bsum[blockIdx.x] = acc4[0] + acc4[1] + acc4[2] + acc4[3];
}

__global__ void scan_bsum(int* __restrict__ bsum, int* __restrict__ offs_end, int nb)
{
    const int lane = threadIdx.x;           // 64 threads, 1 block
    const int v = (lane < nb) ? bsum[lane] : 0;
    int incl = v;
    #pragma unroll
    for (int w = 1; w < 64; w <<= 1) {
        const int t = __shfl_up(incl, w);
        if (lane >= w) incl += t;
    }
    if (lane < nb) bsum[lane] = incl - v;   // exclusive
    if (lane == 63) offs_end[0] = incl;     // total == NE
}

__global__ __launch_bounds__(1024)
void block_scan(const int* __restrict__ deg, const int* __restrict__ bsum,
                int* __restrict__ offs, int* __restrict__ cur, int n)
{
    __shared__ int sh[1024];
    const int tid = threadIdx.x;
    const int gid = blockIdx.x * 1024 + tid;
    const int v = (gid < n) ? deg[gid] : 0;
    sh[tid] = v;
    __syncthreads();
    for (int ofs = 1; ofs < 1024; ofs <<= 1) {
        const int add = (tid >= ofs) ? sh[tid - ofs] : 0;
        __syncthreads();
        sh[tid] += add;
        __syncthreads();
    }
    if (gid < n) {
        const int o = bsum[blockIdx.x] + sh[tid] - v;
        offs[gid] = o;
        cur[gid]  = o;
    }
}

// ---------------- fused: CSR scatter (blocks 0..390) + QKV MFMA GEMM (blocks 391..) ----------
// Scatter: all 8 atomicAdds issued back-to-back (independent), then the 8 dependent
// stores — chain depth 1 atomic round-trip instead of 8.
__global__ __launch_bounds__(256)
void scat_qkv(const int* __restrict__ ei,
              int* __restrict__ cur, int* __restrict__ srcs,
              const float* __restrict__ X,
              const half_t* __restrict__ Wq, const half_t* __restrict__ Wk, const half_t* __restrict__ Wv,
              const float* __restrict__ bq, const float* __restrict__ bk, const float* __restrict__ bv,
              half_t* __restrict__ Qo, half_t* __restrict__ Ko, half_t* __restrict__ Vo)
{
    if (blockIdx.x < SCAT_NB) {
        const int i = (blockIdx.x * 256 + threadIdx.x) * 8;
        if (i >= NE) return;
        const int4 t4a = *(const int4*)(ei + NE + i);
        const int4 t4b = *(const int4*)(ei + NE + i + 4);
        const int4 s4a = *(const int4*)(ei + i);
        const int4 s4b = *(const int4*)(ei + i + 4);
        const int p0 = atomicAdd(&cur[t4a.x], 1);
        const int p1 = atomicAdd(&cur[t4a.y], 1);
        const int p2 = atomicAdd(&cur[t4a.z], 1);
        const int p3 = atomicAdd(&cur[t4a.w], 1);
        const int p4 = atomicAdd(&cur[t4b.x], 1);
        const int p5 = atomicAdd(&cur[t4b.y], 1);
        const int p6 = atomicAdd(&cur[t4b.z], 1);
        const int p7 = atomicAdd(&cur[t4b.w], 1);
        srcs[p0] = s4a.x; srcs[p1] = s4a.y; srcs[p2] = s4a.z; srcs[p3] = s4a.w;
        srcs[p4] = s4b.x; srcs[p5] = s4b.y; srcs[p6] = s4b.z; srcs[p7] = s4b.w;
        return;
    }

    const int bid  = blockIdx.x - SCAT_NB;
    const int lane = threadIdx.x & 63;
    const int wv   = threadIdx.x >> 6;
    const int m0   = bid * 128 + wv * 32;
    const int cl   = lane & 15;           // node within group / W row within tile
    const int kg   = lane >> 4;           // k-slice

    half8_t bx[2][4];
    #pragma unroll
    for (int ng = 0; ng < 2; ++ng) {
        const int row = m0 + ng * 16 + cl;
        #pragma unroll
        for (int ks = 0; ks < 4; ++ks) {
            if (row < N_NODES) {
                const float* xp = X + (size_t)row * DIM + ks * 32 + kg * 8;
                const float4 x0 = *(const float4*)(xp);
                const float4 x1 = *(const float4*)(xp + 4);
                half8_t c;
                c[0] = (_Float16)x0.x; c[1] = (_Float16)x0.y; c[2] = (_Float16)x0.z; c[3] = (_Float16)x0.w;
                c[4] = (_Float16)x1.x; c[5] = (_Float16)x1.y; c[6] = (_Float16)x1.z; c[7] = (_Float16)x1.w;
                bx[ng][ks] = c;
            } else {
                bx[ng][ks] = (half8_t)(_Float16)0.0f;
            }
        }
    }

    const half_t* Ws[3] = {Wq, Wk, Wv};
    const float*  Bs[3] = {bq, bk, bv};
    half_t*       Os[3] = {Qo, Ko, Vo};

    #pragma unroll
    for (int o = 0; o < 3; ++o) {
        const half_t* W = Ws[o];
        half_t* O = Os[o];
        #pragma unroll
        for (int ct = 0; ct < 8; ++ct) {
            f32x4 acc0 = {0.f, 0.f, 0.f, 0.f};
            f32x4 acc1 = {0.f, 0.f, 0.f, 0.f};
            #pragma unroll
            for (int ks = 0; ks < 4; ++ks) {
                const half8_t a = *(const half8_t*)(W + (size_t)(ct * 16 + cl) * DIM + ks * 32 + kg * 8);
                acc0 = __builtin_amdgcn_mfma_f32_16x16x32_f16(a, bx[0][ks], acc0, 0, 0, 0);
                acc1 = __builtin_amdgcn_mfma_f32_16x16x32_f16(a, bx[1][ks], acc1, 0, 0, 0);
            }
            const int c0 = ct * 16 + kg * 4;            // this lane's 4 consecutive outcols
            const float4 b4 = *(const float4*)(Bs[o] + c0);
            const int n0 = m0 + cl;
            if (n0 < N_NODES) {
                half4_t hd4;
                hd4[0] = (_Float16)(acc0[0] + b4.x); hd4[1] = (_Float16)(acc0[1] + b4.y);
                hd4[2] = (_Float16)(acc0[2] + b4.z); hd4[3] = (_Float16)(acc0[3] + b4.w);
                *(half4_t*)(O + (size_t)n0 * DIM + c0) = hd4;
            }
            const int n1 = m0 + 16 + cl;
            if (n1 < N_NODES) {
                half4_t hd4;
                hd4[0] = (_Float16)(acc1[0] + b4.x); hd4[1] = (_Float16)(acc1[1] + b4.y);
                hd4[2] = (_Float16)(acc1[2] + b4.z); hd4[3] = (_Float16)(acc1[3] + b4.w);
                *(half4_t*)(O + (size_t)n1 * DIM + c0) = hd4;
            }
        }
    }
}

// ---------------- output GEMM + bias + residual + LayerNorm, transposed output ----------------
__global__ __launch_bounds__(256)
void out_mfma_ln(const half_t* __restrict__ Ah, const half_t* __restrict__ Wo,
                 const float* __restrict__ bo, const float* __restrict__ X,
                 const float* __restrict__ lng, const float* __restrict__ lnb,
                 float* __restrict__ out)
{
    const int lane = threadIdx.x & 63;
    const int wv   = threadIdx.x >> 6;
    const int m0   = blockIdx.x * 128 + wv * 32;
    const int cl   = lane & 15;
    const int kg   = lane >> 4;

    half8_t bx[2][4];
    #pragma unroll
    for (int ng = 0; ng < 2; ++ng) {
        const int row = m0 + ng * 16 + cl;
        #pragma unroll
        for (int ks = 0; ks < 4; ++ks) {
            if (row < N_NODES)
                bx[ng][ks] = *(const half8_t*)(Ah + (size_t)row * DIM + ks * 32 + kg * 8);
            else
                bx[ng][ks] = (half8_t)(_Float16)0.0f;
        }
    }

    float y[2][8][4];
    #pragma unroll
    for (int ct = 0; ct < 8; ++ct) {
        f32x4 acc0 = {0.f, 0.f, 0.f, 0.f};
        f32x4 acc1 = {0.f, 0.f, 0.f, 0.f};
        #pragma unroll
        for (int ks = 0; ks < 4; ++ks) {
            const half8_t a = *(const half8_t*)(Wo + (size_t)(ct * 16 + cl) * DIM + ks * 32 + kg * 8);
            acc0 = __builtin_amdgcn_mfma_f32_16x16x32_f16(a, bx[0][ks], acc0, 0, 0, 0);
            acc1 = __builtin_amdgcn_mfma_f32_16x16x32_f16(a, bx[1][ks], acc1, 0, 0, 0);
        }
        const int c0 = ct * 16 + kg * 4;
        const float4 b4 = *(const float4*)(bo + c0);
        const int n0 = m0 + cl;
        const int n1 = m0 + 16 + cl;
        float4 x0 = make_float4(0.f, 0.f, 0.f, 0.f), x1 = x0;
        if (n0 < N_NODES) x0 = *(const float4*)(X + (size_t)n0 * DIM + c0);
        if (n1 < N_NODES) x1 = *(const float4*)(X + (size_t)n1 * DIM + c0);
        y[0][ct][0] = acc0[0] + b4.x + x0.x; y[0][ct][1] = acc0[1] + b4.y + x0.y;
        y[0][ct][2] = acc0[2] + b4.z + x0.z; y[0][ct][3] = acc0[3] + b4.w + x0.w;
        y[1][ct][0] = acc1[0] + b4.x + x1.x; y[1][ct][1] = acc1[1] + b4.y + x1.y;
        y[1][ct][2] = acc1[2] + b4.z + x1.z; y[1][ct][3] = acc1[3] + b4.w + x1.w;
    }

    // LayerNorm: node (ng,cl)'s 128 cols live in the 4 lanes sharing cl (kg=0..3), 32 vals each
    #pragma unroll
    for (int ng = 0; ng < 2; ++ng) {
        float s = 0.f, sq = 0.f;
        #pragma unroll
        for (int ct = 0; ct < 8; ++ct)
            #pragma unroll
            for (int j = 0; j < 4; ++j) { const float v = y[ng][ct][j]; s += v; sq += v * v; }
        s += __shfl_xor(s, 16); sq += __shfl_xor(sq, 16);
        s += __shfl_xor(s, 32); sq += __shfl_xor(sq, 32);
        const float mu   = s * (1.0f / 128.0f);
        const float var  = sq * (1.0f / 128.0f) - mu * mu;
        const float rstd = rsqrtf(var + 1e-5f);
        const int node = m0 + ng * 16 + cl;
        if (node < N_NODES) {
            #pragma unroll
            for (int ct = 0; ct < 8; ++ct) {
                const int c0 = ct * 16 + kg * 4;
                const float4 g4 = *(const float4*)(lng + c0);
                const float4 l4 = *(const float4*)(lnb + c0);
                float4 ov;
                ov.x = g4.x * (y[ng][ct][0] - mu) * rstd + l4.x;
                ov.y = g4.y * (y[ng][ct][1] - mu) * rstd + l4.y;
                ov.z = g4.z * (y[ng][ct][2] - mu) * rstd + l4.z;
                ov.w = g4.w * (y[ng][ct][3] - mu) * rstd + l4.w;
                *(float4*)(out + (size_t)node * DIM + c0) = ov;
            }
        }
    }
}

// ---------------- per-node attention + aggregation (1 wave / node, fp16) ----------------
__global__ __launch_bounds__(256)
void attn_agg(const half_t* __restrict__ Qh, const half_t* __restrict__ Kh,
              const half_t* __restrict__ Vh, const int* __restrict__ offs,
              const int* __restrict__ srcs, half_t* __restrict__ AGG)
{
    const int lane = threadIdx.x & 63;
    const int t = blockIdx.x * 4 + (threadIdx.x >> 6);
    if (t >= N_NODES) return;
    const int off = offs[t];
    const int deg = offs[t + 1] - off;
    const int h  = lane & 3;
    const int jl = lane >> 2;
    const int w  = lane >> 5;
    const int dl4 = lane & 31;
    const int hq  = dl4 >> 3;

    half2_t q2[16];
    {
        const half_t* qp = Qh + (size_t)t * DIM + h * DH;
        #pragma unroll
        for (int i = 0; i < 4; ++i) {
            union { half8_t v8; half2_t v2[4]; } u;
            u.v8 = *(const half8_t*)(qp + i * 8);
            #pragma unroll
            for (int p = 0; p < 4; ++p) q2[i * 4 + p] = u.v2[p];
        }
    }

    float ssumL = 0.f;                       // per-lane (score layout)
    half2_t a0 = (half2_t)(_Float16)0.0f;    // dims dl4*4, dl4*4+1
    half2_t a1 = (half2_t)(_Float16)0.0f;    // dims dl4*4+2, dl4*4+3
    const int nch = (deg + 15) >> 4;

    int sA = 0;
    half2_t kA[16] = {};
    {
        const int cnt0 = deg < 16 ? deg : 16;
        if (jl < cnt0) {
            sA = srcs[off + jl];
            const half_t* kp = Kh + (size_t)sA * DIM + h * DH;
            #pragma unroll
            for (int i = 0; i < 4; ++i) {
                union { half8_t v8; half2_t v2[4]; } u;
                u.v8 = *(const half8_t*)(kp + i * 8);
                #pragma unroll
                for (int p = 0; p < 4; ++p) kA[i * 4 + p] = u.v2[p];
            }
        }
    }

    for (int c = 0; c < nch; ++c) {
        const int base = c << 4;
        const int cnt = (deg - base) < 16 ? (deg - base) : 16;

        // prefetch next chunk's srcs + K
        int sB = 0;
        half2_t kB[16] = {};
        if (c + 1 < nch) {
            const int rem = deg - base - 16;
            const int cntn = rem < 16 ? rem : 16;
            if (jl < cntn) {
                sB = srcs[off + base + 16 + jl];
                const half_t* kp = Kh + (size_t)sB * DIM + h * DH;
                #pragma unroll
                for (int i = 0; i < 4; ++i) {
                    union { half8_t v8; half2_t v2[4]; } u;
                    u.v8 = *(const half8_t*)(kp + i * 8);
                    #pragma unroll
                    for (int p = 0; p < 4; ++p) kB[i * 4 + p] = u.v2[p];
                }
            }
        }

        // score for this lane's (edge jl, head h): packed fp16 dot
        float dq = 0.f;
        #pragma unroll
        for (int p = 0; p < 16; ++p)
            dq = __builtin_amdgcn_fdot2(kA[p], q2[p], dq, false);
        const float e = (jl < cnt) ? __expf(dq * SCALEF) : 0.f;
        ssumL += e;

        // packed (e,e) for broadcast
        union { u32 u; half2_t h2; } pe;
        const _Float16 eh = (_Float16)e;
        pe.h2[0] = eh; pe.h2[1] = eh;
        const int peI = (int)pe.u;

        // aggregate: 8 x half4 loads, 2 edges per load instr
        #pragma unroll
        for (int i = 0; i < 8; ++i) {
            const int j = 2 * i + w;                     // this half-wave's edge
            const int sj = __shfl(sA, j * 4);
            union { u32 u; half2_t h2; } e2;
            e2.u = (u32)__shfl(peI, 8 * i + 4 * w + hq);
            union { half4_t v4; half2_t h2[2]; } v;
            v.v4 = *(const half4_t*)(Vh + (size_t)sj * DIM + dl4 * 4);
            a0 = e2.h2 * v.h2[0] + a0;
            a1 = e2.h2 * v.h2[1] + a1;
        }

        sA = sB;
        #pragma unroll
        for (int p = 0; p < 16; ++p) kA[p] = kB[p];
    }

    // combine the two half-waves (lane l and l^32 hold the same dims)
    {
        union { u32 u; half2_t h2; } c0, c1;
        c0.h2 = a0; c1.h2 = a1;
        union { u32 u; half2_t h2; } d0x, d1x;
        d0x.u = (u32)__shfl_xor((int)c0.u, 32);
        d1x.u = (u32)__shfl_xor((int)c1.u, 32);
        a0 = a0 + d0x.h2;
        a1 = a1 + d1x.h2;
    }

    // denominator: reduce ssumL over bits 2..5 (lanes sharing h), broadcast head hq
    float se = ssumL;
    #pragma unroll
    for (int ww = 4; ww < 64; ww <<= 1) se += __shfl_xor(se, ww);
    const float sh = __shfl(se, hq);
    const float inv = 1.0f / (sh + 1e-10f);

    if (lane < 32) {
        half4_t o;
        o[0] = (_Float16)((float)a0[0] * inv);
        o[1] = (_Float16)((float)a0[1] * inv);
        o[2] = (_Float16)((float)a1[0] * inv);
        o[3] = (_Float16)((float)a1[1] * inv);
        *(half4_t*)(AGG + (size_t)t * DIM + dl4 * 4) = o;
    }
}

extern "C" void kernel_launch(void* const* d_in, const int* in_sizes, int n_in,
                              void* d_out, int out_size, void* d_ws, size_t ws_size,
                              hipStream_t stream)
{
    const float* X   = (const float*)d_in[0];
    const float* Wq  = (const float*)d_in[1];
    const float* bq  = (const float*)d_in[2];
    const float* Wk  = (const float*)d_in[3];
    const float* bk  = (const float*)d_in[4];
    const float* Wv  = (const float*)d_in[5];
    const float* bv  = (const float*)d_in[6];
    const float* Wo  = (const float*)d_in[7];
    const float* bo  = (const float*)d_in[8];
    const float* lng = (const float*)d_in[9];
    const float* lnb = (const float*)d_in[10];
    const int*   ei  = (const int*)d_in[11];
    float* out = (float*)d_out;

    const size_t ND = (size_t)N_NODES * DIM;   // 6.4M elems
    half_t* Qh   = (half_t*)d_ws;
    half_t* Kh   = Qh + ND;
    half_t* Vh   = Kh + ND;
    half_t* AGGh = Vh + ND;
    half_t* Wqh  = AGGh + ND;
    half_t* Wkh  = Wqh + DIM * DIM;
    half_t* Wvh  = Wkh + DIM * DIM;
    half_t* Woh  = Wvh + DIM * DIM;
    int* DEG  = (int*)(Woh + DIM * DIM);
    int* CUR  = DEG + N_NODES;
    int* OFFS = CUR + N_NODES;
    int* SRCS = OFFS + N_NODES + 1;
    int* BSUM = SRCS + NE;

    hipMemsetAsync(DEG, 0, N_NODES * sizeof(int), stream);

    // weights -> fp16 + degree histogram (one launch)
    prep_kernel<<<32 + HIST_NB, 256, 0, stream>>>(Wq, Wk, Wv, Wo, Wqh, Wkh, Wvh, Woh,
                                                  ei + NE, DEG);

    // hierarchical scan (coalesced, multi-block) + CUR init
    block_sums<<<NB_SCAN, 256, 0, stream>>>(DEG, BSUM, N_NODES);
    scan_bsum<<<1, 64, 0, stream>>>(BSUM, OFFS + N_NODES, NB_SCAN);
    block_scan<<<NB_SCAN, 1024, 0, stream>>>(DEG, BSUM, OFFS, CUR, N_NODES);

    // CSR scatter + QKV projections (one launch; independent block ranges)
    const int gemmGrid = (N_NODES + 127) / 128;   // 391
    scat_qkv<<<SCAT_NB + gemmGrid, 256, 0, stream>>>(ei, CUR, SRCS,
                                                     X, Wqh, Wkh, Wvh, bq, bk, bv,
                                                     Qh, Kh, Vh);

    // attention + aggregation
    attn_agg<<<(N_NODES + 3) / 4, 256, 0, stream>>>(Qh, Kh, Vh, OFFS, SRCS, AGGh);

    // output projection + residual + LayerNorm
    out_mfma_ln<<<gemmGrid, 256, 0, stream>>>(AGGh, Woh, bo, X, lng, lnb, out);
}

// Round 9
// 157.284 us; speedup vs baseline: 1.3366x; 1.3366x over previous
//
#include <hip/hip_runtime.h>

#define N_NODES 50000
#define DIM 128
#define NH 4
#define DH 32
#define NE 800000
#define SCALEF 0.17677669529663688f   // 1/sqrt(32)

typedef _Float16 half_t;
typedef __attribute__((ext_vector_type(2))) _Float16 half2_t;
typedef __attribute__((ext_vector_type(4))) _Float16 half4_t;
typedef __attribute__((ext_vector_type(8))) _Float16 half8_t;
typedef __attribute__((ext_vector_type(4))) float f32x4;
typedef unsigned short u16;
typedef unsigned int u32;

#define NBKT 391          // buckets of 128 consecutive targets
#define EPB 4096          // edges per hist/scatter block
#define EB 196            // ceil(NE/EPB)

// ---------------- B1: weights->fp16 (blocks 0..31) + bucket histogram (blocks 32..) ----------
__global__ __launch_bounds__(256)
void prep_kernel(const float* __restrict__ w0, const float* __restrict__ w1,
                 const float* __restrict__ w2, const float* __restrict__ w3,
                 half_t* __restrict__ o0, half_t* __restrict__ o1,
                 half_t* __restrict__ o2, half_t* __restrict__ o3,
                 const int* __restrict__ tgt, int* __restrict__ gcnt)
{
    if (blockIdx.x < 32) {
        const float* src; half_t* dst;
        switch (blockIdx.x >> 3) {
            case 0: src = w0; dst = o0; break;
            case 1: src = w1; dst = o1; break;
            case 2: src = w2; dst = o2; break;
            default: src = w3; dst = o3; break;
        }
        const int i = ((blockIdx.x & 7) * 256 + threadIdx.x) * 8;   // 16384 elems per weight
        const float4 a = *(const float4*)(src + i);
        const float4 b = *(const float4*)(src + i + 4);
        half8_t o;
        o[0] = (_Float16)a.x; o[1] = (_Float16)a.y; o[2] = (_Float16)a.z; o[3] = (_Float16)a.w;
        o[4] = (_Float16)b.x; o[5] = (_Float16)b.y; o[6] = (_Float16)b.z; o[7] = (_Float16)b.w;
        *(half8_t*)(dst + i) = o;
        return;
    }
    __shared__ int cnt[512];
    const int tid = threadIdx.x;
    cnt[tid] = 0; cnt[tid + 256] = 0;
    __syncthreads();
    const int base = (blockIdx.x - 32) * EPB;
    #pragma unroll
    for (int r = 0; r < 4; ++r) {
        const int i = base + r * 1024 + tid * 4;
        if (i < NE) {
            const int4 t4 = *(const int4*)(tgt + i);
            atomicAdd(&cnt[t4.x >> 7], 1); atomicAdd(&cnt[t4.y >> 7], 1);
            atomicAdd(&cnt[t4.z >> 7], 1); atomicAdd(&cnt[t4.w >> 7], 1);
        }
    }
    __syncthreads();
    if (cnt[tid])       atomicAdd(&gcnt[tid], cnt[tid]);
    if (cnt[tid + 256]) atomicAdd(&gcnt[tid + 256], cnt[tid + 256]);
}

// ---------------- B2: scan bucket counts -> base/cursor; offs[N]=NE ----------------
__global__ __launch_bounds__(512)
void bucket_scan(const int* __restrict__ gcnt, int* __restrict__ gbase,
                 int* __restrict__ gcur, int* __restrict__ offs)
{
    __shared__ int sh[512];
    const int tid = threadIdx.x;
    const int v = gcnt[tid];
    sh[tid] = v;
    __syncthreads();
    for (int s = 1; s < 512; s <<= 1) {
        const int a = (tid >= s) ? sh[tid - s] : 0;
        __syncthreads();
        sh[tid] += a;
        __syncthreads();
    }
    const int base = sh[tid] - v;   // exclusive
    gbase[tid] = base;
    gcur[tid]  = base;
    if (tid == 0) offs[N_NODES] = NE;
}

// ---------------- B3: bucket scatter (blocks 0..EB-1) + QKV MFMA GEMM (blocks EB..) ----------
__global__ __launch_bounds__(256)
void scat_qkv(const int* __restrict__ ei,
              int* __restrict__ gcur, u32* __restrict__ BE,
              const float* __restrict__ X,
              const half_t* __restrict__ Wq, const half_t* __restrict__ Wk, const half_t* __restrict__ Wv,
              const float* __restrict__ bq, const float* __restrict__ bk, const float* __restrict__ bv,
              half_t* __restrict__ Qo, half_t* __restrict__ Ko, half_t* __restrict__ Vo)
{
    if (blockIdx.x < EB) {
        __shared__ int cnt[512];
        __shared__ int excl[512];
        __shared__ int cursor[512];
        __shared__ int goff[512];
        __shared__ u32 ebuf[EPB];
        __shared__ int stot;
        const int tid = threadIdx.x;
        cnt[tid] = 0; cnt[tid + 256] = 0;
        __syncthreads();
        const int base = blockIdx.x * EPB;
        u32 e[16];
        #pragma unroll
        for (int r = 0; r < 4; ++r) {
            const int i = base + r * 1024 + tid * 4;
            if (i < NE) {
                const int4 t4 = *(const int4*)(ei + NE + i);
                const int4 s4 = *(const int4*)(ei + i);
                e[r*4+0] = ((u32)t4.x << 16) | (u32)s4.x;
                e[r*4+1] = ((u32)t4.y << 16) | (u32)s4.y;
                e[r*4+2] = ((u32)t4.z << 16) | (u32)s4.z;
                e[r*4+3] = ((u32)t4.w << 16) | (u32)s4.w;
                atomicAdd(&cnt[t4.x >> 7], 1); atomicAdd(&cnt[t4.y >> 7], 1);
                atomicAdd(&cnt[t4.z >> 7], 1); atomicAdd(&cnt[t4.w >> 7], 1);
            } else {
                e[r*4+0] = 0xFFFFFFFFu; e[r*4+1] = 0xFFFFFFFFu;
                e[r*4+2] = 0xFFFFFFFFu; e[r*4+3] = 0xFFFFFFFFu;
            }
        }
        __syncthreads();
        // inclusive scan of cnt (512 elems, 2 per thread)
        excl[tid] = cnt[tid]; excl[tid + 256] = cnt[tid + 256];
        __syncthreads();
        for (int s = 1; s < 512; s <<= 1) {
            const int a0 = (tid >= s) ? excl[tid - s] : 0;
            const int a1 = excl[tid + 256 - s];          // tid+256 >= s always (s<=256)
            __syncthreads();
            excl[tid] += a0; excl[tid + 256] += a1;
            __syncthreads();
        }
        const int inc0 = excl[tid], inc1 = excl[tid + 256];
        if (tid == 255) stot = inc1;                     // total valid edges in block
        __syncthreads();
        excl[tid] = inc0 - cnt[tid]; excl[tid + 256] = inc1 - cnt[tid + 256];
        __syncthreads();
        cursor[tid] = excl[tid]; cursor[tid + 256] = excl[tid + 256];
        __syncthreads();
        // place edges into ebuf grouped by bucket
        #pragma unroll
        for (int r = 0; r < 16; ++r) {
            if (e[r] != 0xFFFFFFFFu) {
                const int b = (int)(e[r] >> 16) >> 7;
                const int p = atomicAdd(&cursor[b], 1);
                ebuf[p] = e[r];
            }
        }
        __syncthreads();
        // reserve global chunks (one atomic per nonempty bucket)
        if (cnt[tid])       goff[tid]       = atomicAdd(&gcur[tid], cnt[tid]);
        if (cnt[tid + 256]) goff[tid + 256] = atomicAdd(&gcur[tid + 256], cnt[tid + 256]);
        __syncthreads();
        // coalesced-ish flush: consecutive k -> mostly same bucket -> consecutive dst
        const int total = stot;
        for (int k = tid; k < total; k += 256) {
            const u32 ev = ebuf[k];
            const int b = (int)(ev >> 16) >> 7;
            BE[goff[b] + (k - excl[b])] = ev;
        }
        return;
    }

    const int bid  = blockIdx.x - EB;
    const int lane = threadIdx.x & 63;
    const int wv   = threadIdx.x >> 6;
    const int m0   = bid * 128 + wv * 32;
    const int cl   = lane & 15;           // node within group / W row within tile
    const int kg   = lane >> 4;           // k-slice

    half8_t bx[2][4];
    #pragma unroll
    for (int ng = 0; ng < 2; ++ng) {
        const int row = m0 + ng * 16 + cl;
        #pragma unroll
        for (int ks = 0; ks < 4; ++ks) {
            if (row < N_NODES) {
                const float* xp = X + (size_t)row * DIM + ks * 32 + kg * 8;
                const float4 x0 = *(const float4*)(xp);
                const float4 x1 = *(const float4*)(xp + 4);
                half8_t c;
                c[0] = (_Float16)x0.x; c[1] = (_Float16)x0.y; c[2] = (_Float16)x0.z; c[3] = (_Float16)x0.w;
                c[4] = (_Float16)x1.x; c[5] = (_Float16)x1.y; c[6] = (_Float16)x1.z; c[7] = (_Float16)x1.w;
                bx[ng][ks] = c;
            } else {
                bx[ng][ks] = (half8_t)(_Float16)0.0f;
            }
        }
    }

    const half_t* Ws[3] = {Wq, Wk, Wv};
    const float*  Bs[3] = {bq, bk, bv};
    half_t*       Os[3] = {Qo, Ko, Vo};

    #pragma unroll
    for (int o = 0; o < 3; ++o) {
        const half_t* W = Ws[o];
        half_t* O = Os[o];
        #pragma unroll
        for (int ct = 0; ct < 8; ++ct) {
            f32x4 acc0 = {0.f, 0.f, 0.f, 0.f};
            f32x4 acc1 = {0.f, 0.f, 0.f, 0.f};
            #pragma unroll
            for (int ks = 0; ks < 4; ++ks) {
                const half8_t a = *(const half8_t*)(W + (size_t)(ct * 16 + cl) * DIM + ks * 32 + kg * 8);
                acc0 = __builtin_amdgcn_mfma_f32_16x16x32_f16(a, bx[0][ks], acc0, 0, 0, 0);
                acc1 = __builtin_amdgcn_mfma_f32_16x16x32_f16(a, bx[1][ks], acc1, 0, 0, 0);
            }
            const int c0 = ct * 16 + kg * 4;            // this lane's 4 consecutive outcols
            const float4 b4 = *(const float4*)(Bs[o] + c0);
            const int n0 = m0 + cl;
            if (n0 < N_NODES) {
                half4_t hd4;
                hd4[0] = (_Float16)(acc0[0] + b4.x); hd4[1] = (_Float16)(acc0[1] + b4.y);
                hd4[2] = (_Float16)(acc0[2] + b4.z); hd4[3] = (_Float16)(acc0[3] + b4.w);
                *(half4_t*)(O + (size_t)n0 * DIM + c0) = hd4;
            }
            const int n1 = m0 + 16 + cl;
            if (n1 < N_NODES) {
                half4_t hd4;
                hd4[0] = (_Float16)(acc1[0] + b4.x); hd4[1] = (_Float16)(acc1[1] + b4.y);
                hd4[2] = (_Float16)(acc1[2] + b4.z); hd4[3] = (_Float16)(acc1[3] + b4.w);
                *(half4_t*)(O + (size_t)n1 * DIM + c0) = hd4;
            }
        }
    }
}

// ---------------- B4: per-bucket CSR finalize: offs + srcs (LDS atomics only) ----------------
__global__ __launch_bounds__(256)
void csr_build(const u32* __restrict__ BE, const int* __restrict__ gbase,
               int* __restrict__ offs, int* __restrict__ srcs)
{
    __shared__ int dcnt[128], dof[128], dcur[128];
    const int b   = blockIdx.x;
    const int tid = threadIdx.x;
    const int t0  = b << 7;
    const int nt  = (N_NODES - t0) < 128 ? (N_NODES - t0) : 128;
    const int base = gbase[b];
    const int end  = gbase[b + 1];
    if (tid < 128) dcnt[tid] = 0;
    __syncthreads();
    for (int k = base + tid; k < end; k += 256)
        atomicAdd(&dcnt[(int)(BE[k] >> 16) - t0], 1);
    __syncthreads();
    if (tid < 128) dof[tid] = dcnt[tid];
    __syncthreads();
    for (int s = 1; s < 128; s <<= 1) {
        int a = 0;
        if (tid < 128 && tid >= s) a = dof[tid - s];
        __syncthreads();
        if (tid < 128) dof[tid] += a;
        __syncthreads();
    }
    if (tid < 128) {
        const int ex = dof[tid] - dcnt[tid];
        dof[tid] = ex;
        dcur[tid] = 0;
        if (tid < nt) offs[t0 + tid] = base + ex;
    }
    __syncthreads();
    for (int k = base + tid; k < end; k += 256) {
        const u32 ev = BE[k];
        const int tl = (int)(ev >> 16) - t0;
        const int p  = atomicAdd(&dcur[tl], 1);
        srcs[base + dof[tl] + p] = (int)(ev & 0xFFFFu);
    }
}

// ---------------- output GEMM + bias + residual + LayerNorm, transposed output ----------------
__global__ __launch_bounds__(256)
void out_mfma_ln(const half_t* __restrict__ Ah, const half_t* __restrict__ Wo,
                 const float* __restrict__ bo, const float* __restrict__ X,
                 const float* __restrict__ lng, const float* __restrict__ lnb,
                 float* __restrict__ out)
{
    const int lane = threadIdx.x & 63;
    const int wv   = threadIdx.x >> 6;
    const int m0   = blockIdx.x * 128 + wv * 32;
    const int cl   = lane & 15;
    const int kg   = lane >> 4;

    half8_t bx[2][4];
    #pragma unroll
    for (int ng = 0; ng < 2; ++ng) {
        const int row = m0 + ng * 16 + cl;
        #pragma unroll
        for (int ks = 0; ks < 4; ++ks) {
            if (row < N_NODES)
                bx[ng][ks] = *(const half8_t*)(Ah + (size_t)row * DIM + ks * 32 + kg * 8);
            else
                bx[ng][ks] = (half8_t)(_Float16)0.0f;
        }
    }

    float y[2][8][4];
    #pragma unroll
    for (int ct = 0; ct < 8; ++ct) {
        f32x4 acc0 = {0.f, 0.f, 0.f, 0.f};
        f32x4 acc1 = {0.f, 0.f, 0.f, 0.f};
        #pragma unroll
        for (int ks = 0; ks < 4; ++ks) {
            const half8_t a = *(const half8_t*)(Wo + (size_t)(ct * 16 + cl) * DIM + ks * 32 + kg * 8);
            acc0 = __builtin_amdgcn_mfma_f32_16x16x32_f16(a, bx[0][ks], acc0, 0, 0, 0);
            acc1 = __builtin_amdgcn_mfma_f32_16x16x32_f16(a, bx[1][ks], acc1, 0, 0, 0);
        }
        const int c0 = ct * 16 + kg * 4;
        const float4 b4 = *(const float4*)(bo + c0);
        const int n0 = m0 + cl;
        const int n1 = m0 + 16 + cl;
        float4 x0 = make_float4(0.f, 0.f, 0.f, 0.f), x1 = x0;
        if (n0 < N_NODES) x0 = *(const float4*)(X + (size_t)n0 * DIM + c0);
        if (n1 < N_NODES) x1 = *(const float4*)(X + (size_t)n1 * DIM + c0);
        y[0][ct][0] = acc0[0] + b4.x + x0.x; y[0][ct][1] = acc0[1] + b4.y + x0.y;
        y[0][ct][2] = acc0[2] + b4.z + x0.z; y[0][ct][3] = acc0[3] + b4.w + x0.w;
        y[1][ct][0] = acc1[0] + b4.x + x1.x; y[1][ct][1] = acc1[1] + b4.y + x1.y;
        y[1][ct][2] = acc1[2] + b4.z + x1.z; y[1][ct][3] = acc1[3] + b4.w + x1.w;
    }

    // LayerNorm: node (ng,cl)'s 128 cols live in the 4 lanes sharing cl (kg=0..3), 32 vals each
    #pragma unroll
    for (int ng = 0; ng < 2; ++ng) {
        float s = 0.f, sq = 0.f;
        #pragma unroll
        for (int ct = 0; ct < 8; ++ct)
            #pragma unroll
            for (int j = 0; j < 4; ++j) { const float v = y[ng][ct][j]; s += v; sq += v * v; }
        s += __shfl_xor(s, 16); sq += __shfl_xor(sq, 16);
        s += __shfl_xor(s, 32); sq += __shfl_xor(sq, 32);
        const float mu   = s * (1.0f / 128.0f);
        const float var  = sq * (1.0f / 128.0f) - mu * mu;
        const float rstd = rsqrtf(var + 1e-5f);
        const int node = m0 + ng * 16 + cl;
        if (node < N_NODES) {
            #pragma unroll
            for (int ct = 0; ct < 8; ++ct) {
                const int c0 = ct * 16 + kg * 4;
                const float4 g4 = *(const float4*)(lng + c0);
                const float4 l4 = *(const float4*)(lnb + c0);
                float4 ov;
                ov.x = g4.x * (y[ng][ct][0] - mu) * rstd + l4.x;
                ov.y = g4.y * (y[ng][ct][1] - mu) * rstd + l4.y;
                ov.z = g4.z * (y[ng][ct][2] - mu) * rstd + l4.z;
                ov.w = g4.w * (y[ng][ct][3] - mu) * rstd + l4.w;
                *(float4*)(out + (size_t)node * DIM + c0) = ov;
            }
        }
    }
}

// ---------------- per-node attention + aggregation (1 wave / node, fp16) ----------------
__global__ __launch_bounds__(256)
void attn_agg(const half_t* __restrict__ Qh, const half_t* __restrict__ Kh,
              const half_t* __restrict__ Vh, const int* __restrict__ offs,
              const int* __restrict__ srcs, half_t* __restrict__ AGG)
{
    const int lane = threadIdx.x & 63;
    const int t = blockIdx.x * 4 + (threadIdx.x >> 6);
    if (t >= N_NODES) return;
    const int off = offs[t];
    const int deg = offs[t + 1] - off;
    const int h  = lane & 3;
    const int jl = lane >> 2;
    const int w  = lane >> 5;
    const int dl4 = lane & 31;
    const int hq  = dl4 >> 3;

    half2_t q2[16];
    {
        const half_t* qp = Qh + (size_t)t * DIM + h * DH;
        #pragma unroll
        for (int i = 0; i < 4; ++i) {
            union { half8_t v8; half2_t v2[4]; } u;
            u.v8 = *(const half8_t*)(qp + i * 8);
            #pragma unroll
            for (int p = 0; p < 4; ++p) q2[i * 4 + p] = u.v2[p];
        }
    }

    float ssumL = 0.f;                       // per-lane (score layout)
    half2_t a0 = (half2_t)(_Float16)0.0f;    // dims dl4*4, dl4*4+1
    half2_t a1 = (half2_t)(_Float16)0.0f;    // dims dl4*4+2, dl4*4+3
    const int nch = (deg + 15) >> 4;

    int sA = 0;
    half2_t kA[16] = {};
    {
        const int cnt0 = deg < 16 ? deg : 16;
        if (jl < cnt0) {
            sA = srcs[off + jl];
            const half_t* kp = Kh + (size_t)sA * DIM + h * DH;
            #pragma unroll
            for (int i = 0; i < 4; ++i) {
                union { half8_t v8; half2_t v2[4]; } u;
                u.v8 = *(const half8_t*)(kp + i * 8);
                #pragma unroll
                for (int p = 0; p < 4; ++p) kA[i * 4 + p] = u.v2[p];
            }
        }
    }

    for (int c = 0; c < nch; ++c) {
        const int base = c << 4;
        const int cnt = (deg - base) < 16 ? (deg - base) : 16;

        // prefetch next chunk's srcs + K
        int sB = 0;
        half2_t kB[16] = {};
        if (c + 1 < nch) {
            const int rem = deg - base - 16;
            const int cntn = rem < 16 ? rem : 16;
            if (jl < cntn) {
                sB = srcs[off + base + 16 + jl];
                const half_t* kp = Kh + (size_t)sB * DIM + h * DH;
                #pragma unroll
                for (int i = 0; i < 4; ++i) {
                    union { half8_t v8; half2_t v2[4]; } u;
                    u.v8 = *(const half8_t*)(kp + i * 8);
                    #pragma unroll
                    for (int p = 0; p < 4; ++p) kB[i * 4 + p] = u.v2[p];
                }
            }
        }

        // score for this lane's (edge jl, head h): packed fp16 dot
        float dq = 0.f;
        #pragma unroll
        for (int p = 0; p < 16; ++p)
            dq = __builtin_amdgcn_fdot2(kA[p], q2[p], dq, false);
        const float e = (jl < cnt) ? __expf(dq * SCALEF) : 0.f;
        ssumL += e;

        // packed (e,e) for broadcast
        union { u32 u; half2_t h2; } pe;
        const _Float16 eh = (_Float16)e;
        pe.h2[0] = eh; pe.h2[1] = eh;
        const int peI = (int)pe.u;

        // aggregate: 8 x half4 loads, 2 edges per load instr
        #pragma unroll
        for (int i = 0; i < 8; ++i) {
            const int j = 2 * i + w;                     // this half-wave's edge
            const int sj = __shfl(sA, j * 4);
            union { u32 u; half2_t h2; } e2;
            e2.u = (u32)__shfl(peI, 8 * i + 4 * w + hq);
            union { half4_t v4; half2_t h2[2]; } v;
            v.v4 = *(const half4_t*)(Vh + (size_t)sj * DIM + dl4 * 4);
            a0 = e2.h2 * v.h2[0] + a0;
            a1 = e2.h2 * v.h2[1] + a1;
        }

        sA = sB;
        #pragma unroll
        for (int p = 0; p < 16; ++p) kA[p] = kB[p];
    }

    // combine the two half-waves (lane l and l^32 hold the same dims)
    {
        union { u32 u; half2_t h2; } c0, c1;
        c0.h2 = a0; c1.h2 = a1;
        union { u32 u; half2_t h2; } d0x, d1x;
        d0x.u = (u32)__shfl_xor((int)c0.u, 32);
        d1x.u = (u32)__shfl_xor((int)c1.u, 32);
        a0 = a0 + d0x.h2;
        a1 = a1 + d1x.h2;
    }

    // denominator: reduce ssumL over bits 2..5 (lanes sharing h), broadcast head hq
    float se = ssumL;
    #pragma unroll
    for (int ww = 4; ww < 64; ww <<= 1) se += __shfl_xor(se, ww);
    const float sh = __shfl(se, hq);
    const float inv = 1.0f / (sh + 1e-10f);

    if (lane < 32) {
        half4_t o;
        o[0] = (_Float16)((float)a0[0] * inv);
        o[1] = (_Float16)((float)a0[1] * inv);
        o[2] = (_Float16)((float)a1[0] * inv);
        o[3] = (_Float16)((float)a1[1] * inv);
        *(half4_t*)(AGG + (size_t)t * DIM + dl4 * 4) = o;
    }
}

extern "C" void kernel_launch(void* const* d_in, const int* in_sizes, int n_in,
                              void* d_out, int out_size, void* d_ws, size_t ws_size,
                              hipStream_t stream)
{
    const float* X   = (const float*)d_in[0];
    const float* Wq  = (const float*)d_in[1];
    const float* bq  = (const float*)d_in[2];
    const float* Wk  = (const float*)d_in[3];
    const float* bk  = (const float*)d_in[4];
    const float* Wv  = (const float*)d_in[5];
    const float* bv  = (const float*)d_in[6];
    const float* Wo  = (const float*)d_in[7];
    const float* bo  = (const float*)d_in[8];
    const float* lng = (const float*)d_in[9];
    const float* lnb = (const float*)d_in[10];
    const int*   ei  = (const int*)d_in[11];
    float* out = (float*)d_out;

    const size_t ND = (size_t)N_NODES * DIM;   // 6.4M elems
    half_t* Qh   = (half_t*)d_ws;
    half_t* Kh   = Qh + ND;
    half_t* Vh   = Kh + ND;
    half_t* AGGh = Vh + ND;
    half_t* Wqh  = AGGh + ND;
    half_t* Wkh  = Wqh + DIM * DIM;
    half_t* Wvh  = Wkh + DIM * DIM;
    half_t* Woh  = Wvh + DIM * DIM;
    u32* BE   = (u32*)(Woh + DIM * DIM);
    int* OFFS = (int*)(BE + NE);
    int* SRCS = OFFS + N_NODES + 1;
    int* GCNT = SRCS + NE;
    int* GBASE = GCNT + 512;
    int* GCUR  = GBASE + 512;

    hipMemsetAsync(GCNT, 0, 512 * sizeof(int), stream);

    // weights -> fp16 + bucket histogram (one launch)
    prep_kernel<<<32 + EB, 256, 0, stream>>>(Wq, Wk, Wv, Wo, Wqh, Wkh, Wvh, Woh,
                                             ei + NE, GCNT);

    // bucket scan -> base/cursor
    bucket_scan<<<1, 512, 0, stream>>>(GCNT, GBASE, GCUR, OFFS);

    // bucket scatter + QKV projections (one launch; independent block ranges)
    const int gemmGrid = (N_NODES + 127) / 128;   // 391
    scat_qkv<<<EB + gemmGrid, 256, 0, stream>>>(ei, GCUR, BE,
                                                X, Wqh, Wkh, Wvh, bq, bk, bv,
                                                Qh, Kh, Vh);

    // per-bucket CSR finalize (LDS atomics only)
    csr_build<<<NBKT, 256, 0, stream>>>(BE, GBASE, OFFS, SRCS);

    // attention + aggregation
    attn_agg<<<(N_NODES + 3) / 4, 256, 0, stream>>>(Qh, Kh, Vh, OFFS, SRCS, AGGh);

    // output projection + residual + LayerNorm
    out_mfma_ln<<<gemmGrid, 256, 0, stream>>>(AGGh, Woh, bo, X, lng, lnb, out);
}

// Round 11
// 155.707 us; speedup vs baseline: 1.3501x; 1.0101x over previous
//
#include <hip/hip_runtime.h>

#define N_NODES 50000
#define DIM 128
#define NH 4
#define DH 32
#define NE 800000
#define SCALEF 0.17677669529663688f   // 1/sqrt(32)

typedef _Float16 half_t;
typedef __attribute__((ext_vector_type(2))) _Float16 half2_t;
typedef __attribute__((ext_vector_type(4))) _Float16 half4_t;
typedef __attribute__((ext_vector_type(8))) _Float16 half8_t;
typedef __attribute__((ext_vector_type(4))) float f32x4;
typedef unsigned short u16;
typedef unsigned int u32;

#define NBKT 391          // buckets of 128 consecutive targets
#define EPB 4096          // edges per hist/scatter block
#define EB 196            // ceil(NE/EPB)

// ---------------- B1: weights->fp16 (blocks 0..31) + bucket histogram (blocks 32..) ----------
__global__ __launch_bounds__(256)
void prep_kernel(const float* __restrict__ w0, const float* __restrict__ w1,
                 const float* __restrict__ w2, const float* __restrict__ w3,
                 half_t* __restrict__ o0, half_t* __restrict__ o1,
                 half_t* __restrict__ o2, half_t* __restrict__ o3,
                 const int* __restrict__ tgt, int* __restrict__ gcnt)
{
    if (blockIdx.x < 32) {
        const float* src; half_t* dst;
        switch (blockIdx.x >> 3) {
            case 0: src = w0; dst = o0; break;
            case 1: src = w1; dst = o1; break;
            case 2: src = w2; dst = o2; break;
            default: src = w3; dst = o3; break;
        }
        const int i = ((blockIdx.x & 7) * 256 + threadIdx.x) * 8;   // 16384 elems per weight
        const float4 a = *(const float4*)(src + i);
        const float4 b = *(const float4*)(src + i + 4);
        half8_t o;
        o[0] = (_Float16)a.x; o[1] = (_Float16)a.y; o[2] = (_Float16)a.z; o[3] = (_Float16)a.w;
        o[4] = (_Float16)b.x; o[5] = (_Float16)b.y; o[6] = (_Float16)b.z; o[7] = (_Float16)b.w;
        *(half8_t*)(dst + i) = o;
        return;
    }
    __shared__ int cnt[512];
    const int tid = threadIdx.x;
    cnt[tid] = 0; cnt[tid + 256] = 0;
    __syncthreads();
    const int base = (blockIdx.x - 32) * EPB;
    #pragma unroll
    for (int r = 0; r < 4; ++r) {
        const int i = base + r * 1024 + tid * 4;
        if (i < NE) {
            const int4 t4 = *(const int4*)(tgt + i);
            atomicAdd(&cnt[t4.x >> 7], 1); atomicAdd(&cnt[t4.y >> 7], 1);
            atomicAdd(&cnt[t4.z >> 7], 1); atomicAdd(&cnt[t4.w >> 7], 1);
        }
    }
    __syncthreads();
    if (cnt[tid])       atomicAdd(&gcnt[tid], cnt[tid]);
    if (cnt[tid + 256]) atomicAdd(&gcnt[tid + 256], cnt[tid + 256]);
}

// ---------------- B2: scan bucket counts -> base/cursor; offs[N]=NE ----------------
__global__ __launch_bounds__(512)
void bucket_scan(const int* __restrict__ gcnt, int* __restrict__ gbase,
                 int* __restrict__ gcur, int* __restrict__ offs)
{
    __shared__ int sh[512];
    const int tid = threadIdx.x;
    const int v = gcnt[tid];
    sh[tid] = v;
    __syncthreads();
    for (int s = 1; s < 512; s <<= 1) {
        const int a = (tid >= s) ? sh[tid - s] : 0;
        __syncthreads();
        sh[tid] += a;
        __syncthreads();
    }
    const int base = sh[tid] - v;   // exclusive
    gbase[tid] = base;
    gcur[tid]  = base;
    if (tid == 0) offs[N_NODES] = NE;
}

// ---------------- B3: bucket scatter (blocks 0..EB-1) + QKV MFMA GEMM (blocks EB..) ----------
__global__ __launch_bounds__(256)
void scat_qkv(const int* __restrict__ ei,
              int* __restrict__ gcur, u32* __restrict__ BE,
              const float* __restrict__ X,
              const half_t* __restrict__ Wq, const half_t* __restrict__ Wk, const half_t* __restrict__ Wv,
              const float* __restrict__ bq, const float* __restrict__ bk, const float* __restrict__ bv,
              half_t* __restrict__ Qo, half_t* __restrict__ Ko, half_t* __restrict__ Vo)
{
    if (blockIdx.x < EB) {
        __shared__ int cnt[512];
        __shared__ int excl[512];
        __shared__ int cursor[512];
        __shared__ int goff[512];
        __shared__ u32 ebuf[EPB];
        __shared__ int stot;
        const int tid = threadIdx.x;
        cnt[tid] = 0; cnt[tid + 256] = 0;
        __syncthreads();
        const int base = blockIdx.x * EPB;
        u32 e[16];
        #pragma unroll
        for (int r = 0; r < 4; ++r) {
            const int i = base + r * 1024 + tid * 4;
            if (i < NE) {
                const int4 t4 = *(const int4*)(ei + NE + i);
                const int4 s4 = *(const int4*)(ei + i);
                e[r*4+0] = ((u32)t4.x << 16) | (u32)s4.x;
                e[r*4+1] = ((u32)t4.y << 16) | (u32)s4.y;
                e[r*4+2] = ((u32)t4.z << 16) | (u32)s4.z;
                e[r*4+3] = ((u32)t4.w << 16) | (u32)s4.w;
                atomicAdd(&cnt[t4.x >> 7], 1); atomicAdd(&cnt[t4.y >> 7], 1);
                atomicAdd(&cnt[t4.z >> 7], 1); atomicAdd(&cnt[t4.w >> 7], 1);
            } else {
                e[r*4+0] = 0xFFFFFFFFu; e[r*4+1] = 0xFFFFFFFFu;
                e[r*4+2] = 0xFFFFFFFFu; e[r*4+3] = 0xFFFFFFFFu;
            }
        }
        __syncthreads();
        excl[tid] = cnt[tid]; excl[tid + 256] = cnt[tid + 256];
        __syncthreads();
        for (int s = 1; s < 512; s <<= 1) {
            const int a0 = (tid >= s) ? excl[tid - s] : 0;
            const int a1 = excl[tid + 256 - s];
            __syncthreads();
            excl[tid] += a0; excl[tid + 256] += a1;
            __syncthreads();
        }
        const int inc0 = excl[tid], inc1 = excl[tid + 256];
        if (tid == 255) stot = inc1;
        __syncthreads();
        excl[tid] = inc0 - cnt[tid]; excl[tid + 256] = inc1 - cnt[tid + 256];
        __syncthreads();
        cursor[tid] = excl[tid]; cursor[tid + 256] = excl[tid + 256];
        __syncthreads();
        #pragma unroll
        for (int r = 0; r < 16; ++r) {
            if (e[r] != 0xFFFFFFFFu) {
                const int b = (int)(e[r] >> 16) >> 7;
                const int p = atomicAdd(&cursor[b], 1);
                ebuf[p] = e[r];
            }
        }
        __syncthreads();
        if (cnt[tid])       goff[tid]       = atomicAdd(&gcur[tid], cnt[tid]);
        if (cnt[tid + 256]) goff[tid + 256] = atomicAdd(&gcur[tid + 256], cnt[tid + 256]);
        __syncthreads();
        const int total = stot;
        for (int k = tid; k < total; k += 256) {
            const u32 ev = ebuf[k];
            const int b = (int)(ev >> 16) >> 7;
            BE[goff[b] + (k - excl[b])] = ev;
        }
        return;
    }

    const int bid  = blockIdx.x - EB;
    const int lane = threadIdx.x & 63;
    const int wv   = threadIdx.x >> 6;
    const int m0   = bid * 128 + wv * 32;
    const int cl   = lane & 15;           // node within group / W row within tile
    const int kg   = lane >> 4;           // k-slice

    half8_t bx[2][4];
    #pragma unroll
    for (int ng = 0; ng < 2; ++ng) {
        const int row = m0 + ng * 16 + cl;
        #pragma unroll
        for (int ks = 0; ks < 4; ++ks) {
            if (row < N_NODES) {
                const float* xp = X + (size_t)row * DIM + ks * 32 + kg * 8;
                const float4 x0 = *(const float4*)(xp);
                const float4 x1 = *(const float4*)(xp + 4);
                half8_t c;
                c[0] = (_Float16)x0.x; c[1] = (_Float16)x0.y; c[2] = (_Float16)x0.z; c[3] = (_Float16)x0.w;
                c[4] = (_Float16)x1.x; c[5] = (_Float16)x1.y; c[6] = (_Float16)x1.z; c[7] = (_Float16)x1.w;
                bx[ng][ks] = c;
            } else {
                bx[ng][ks] = (half8_t)(_Float16)0.0f;
            }
        }
    }

    const half_t* Ws[3] = {Wq, Wk, Wv};
    const float*  Bs[3] = {bq, bk, bv};
    half_t*       Os[3] = {Qo, Ko, Vo};

    #pragma unroll
    for (int o = 0; o < 3; ++o) {
        const half_t* W = Ws[o];
        half_t* O = Os[o];
        #pragma unroll
        for (int ct = 0; ct < 8; ++ct) {
            f32x4 acc0 = {0.f, 0.f, 0.f, 0.f};
            f32x4 acc1 = {0.f, 0.f, 0.f, 0.f};
            #pragma unroll
            for (int ks = 0; ks < 4; ++ks) {
                const half8_t a = *(const half8_t*)(W + (size_t)(ct * 16 + cl) * DIM + ks * 32 + kg * 8);
                acc0 = __builtin_amdgcn_mfma_f32_16x16x32_f16(a, bx[0][ks], acc0, 0, 0, 0);
                acc1 = __builtin_amdgcn_mfma_f32_16x16x32_f16(a, bx[1][ks], acc1, 0, 0, 0);
            }
            const int c0 = ct * 16 + kg * 4;            // this lane's 4 consecutive outcols
            const float4 b4 = *(const float4*)(Bs[o] + c0);
            const int n0 = m0 + cl;
            if (n0 < N_NODES) {
                half4_t hd4;
                hd4[0] = (_Float16)(acc0[0] + b4.x); hd4[1] = (_Float16)(acc0[1] + b4.y);
                hd4[2] = (_Float16)(acc0[2] + b4.z); hd4[3] = (_Float16)(acc0[3] + b4.w);
                *(half4_t*)(O + (size_t)n0 * DIM + c0) = hd4;
            }
            const int n1 = m0 + 16 + cl;
            if (n1 < N_NODES) {
                half4_t hd4;
                hd4[0] = (_Float16)(acc1[0] + b4.x); hd4[1] = (_Float16)(acc1[1] + b4.y);
                hd4[2] = (_Float16)(acc1[2] + b4.z); hd4[3] = (_Float16)(acc1[3] + b4.w);
                *(half4_t*)(O + (size_t)n1 * DIM + c0) = hd4;
            }
        }
    }
}

// ---------------- B4: per-bucket CSR finalize: offs + srcs (LDS atomics only) ----------------
__global__ __launch_bounds__(256)
void csr_build(const u32* __restrict__ BE, const int* __restrict__ gbase,
               int* __restrict__ offs, int* __restrict__ srcs)
{
    __shared__ int dcnt[128], dof[128], dcur[128];
    const int b   = blockIdx.x;
    const int tid = threadIdx.x;
    const int t0  = b << 7;
    const int nt  = (N_NODES - t0) < 128 ? (N_NODES - t0) : 128;
    const int base = gbase[b];
    const int end  = gbase[b + 1];
    if (tid < 128) dcnt[tid] = 0;
    __syncthreads();
    for (int k = base + tid; k < end; k += 256)
        atomicAdd(&dcnt[(int)(BE[k] >> 16) - t0], 1);
    __syncthreads();
    if (tid < 128) dof[tid] = dcnt[tid];
    __syncthreads();
    for (int s = 1; s < 128; s <<= 1) {
        int a = 0;
        if (tid < 128 && tid >= s) a = dof[tid - s];
        __syncthreads();
        if (tid < 128) dof[tid] += a;
        __syncthreads();
    }
    if (tid < 128) {
        const int ex = dof[tid] - dcnt[tid];
        dof[tid] = ex;
        dcur[tid] = 0;
        if (tid < nt) offs[t0 + tid] = base + ex;
    }
    __syncthreads();
    for (int k = base + tid; k < end; k += 256) {
        const u32 ev = BE[k];
        const int tl = (int)(ev >> 16) - t0;
        const int p  = atomicAdd(&dcur[tl], 1);
        srcs[base + dof[tl] + p] = (int)(ev & 0xFFFFu);
    }
}

// ---------------- output GEMM + bias + residual + LayerNorm, transposed output ----------------
__global__ __launch_bounds__(256)
void out_mfma_ln(const half_t* __restrict__ Ah, const half_t* __restrict__ Wo,
                 const float* __restrict__ bo, const float* __restrict__ X,
                 const float* __restrict__ lng, const float* __restrict__ lnb,
                 float* __restrict__ out)
{
    const int lane = threadIdx.x & 63;
    const int wv   = threadIdx.x >> 6;
    const int m0   = blockIdx.x * 128 + wv * 32;
    const int cl   = lane & 15;
    const int kg   = lane >> 4;

    half8_t bx[2][4];
    #pragma unroll
    for (int ng = 0; ng < 2; ++ng) {
        const int row = m0 + ng * 16 + cl;
        #pragma unroll
        for (int ks = 0; ks < 4; ++ks) {
            if (row < N_NODES)
                bx[ng][ks] = *(const half8_t*)(Ah + (size_t)row * DIM + ks * 32 + kg * 8);
            else
                bx[ng][ks] = (half8_t)(_Float16)0.0f;
        }
    }

    float y[2][8][4];
    #pragma unroll
    for (int ct = 0; ct < 8; ++ct) {
        f32x4 acc0 = {0.f, 0.f, 0.f, 0.f};
        f32x4 acc1 = {0.f, 0.f, 0.f, 0.f};
        #pragma unroll
        for (int ks = 0; ks < 4; ++ks) {
            const half8_t a = *(const half8_t*)(Wo + (size_t)(ct * 16 + cl) * DIM + ks * 32 + kg * 8);
            acc0 = __builtin_amdgcn_mfma_f32_16x16x32_f16(a, bx[0][ks], acc0, 0, 0, 0);
            acc1 = __builtin_amdgcn_mfma_f32_16x16x32_f16(a, bx[1][ks], acc1, 0, 0, 0);
        }
        const int c0 = ct * 16 + kg * 4;
        const float4 b4 = *(const float4*)(bo + c0);
        const int n0 = m0 + cl;
        const int n1 = m0 + 16 + cl;
        float4 x0 = make_float4(0.f, 0.f, 0.f, 0.f), x1 = x0;
        if (n0 < N_NODES) x0 = *(const float4*)(X + (size_t)n0 * DIM + c0);
        if (n1 < N_NODES) x1 = *(const float4*)(X + (size_t)n1 * DIM + c0);
        y[0][ct][0] = acc0[0] + b4.x + x0.x; y[0][ct][1] = acc0[1] + b4.y + x0.y;
        y[0][ct][2] = acc0[2] + b4.z + x0.z; y[0][ct][3] = acc0[3] + b4.w + x0.w;
        y[1][ct][0] = acc1[0] + b4.x + x1.x; y[1][ct][1] = acc1[1] + b4.y + x1.y;
        y[1][ct][2] = acc1[2] + b4.z + x1.z; y[1][ct][3] = acc1[3] + b4.w + x1.w;
    }

    #pragma unroll
    for (int ng = 0; ng < 2; ++ng) {
        float s = 0.f, sq = 0.f;
        #pragma unroll
        for (int ct = 0; ct < 8; ++ct)
            #pragma unroll
            for (int j = 0; j < 4; ++j) { const float v = y[ng][ct][j]; s += v; sq += v * v; }
        s += __shfl_xor(s, 16); sq += __shfl_xor(sq, 16);
        s += __shfl_xor(s, 32); sq += __shfl_xor(sq, 32);
        const float mu   = s * (1.0f / 128.0f);
        const float var  = sq * (1.0f / 128.0f) - mu * mu;
        const float rstd = rsqrtf(var + 1e-5f);
        const int node = m0 + ng * 16 + cl;
        if (node < N_NODES) {
            #pragma unroll
            for (int ct = 0; ct < 8; ++ct) {
                const int c0 = ct * 16 + kg * 4;
                const float4 g4 = *(const float4*)(lng + c0);
                const float4 l4 = *(const float4*)(lnb + c0);
                float4 ov;
                ov.x = g4.x * (y[ng][ct][0] - mu) * rstd + l4.x;
                ov.y = g4.y * (y[ng][ct][1] - mu) * rstd + l4.y;
                ov.z = g4.z * (y[ng][ct][2] - mu) * rstd + l4.z;
                ov.w = g4.w * (y[ng][ct][3] - mu) * rstd + l4.w;
                *(float4*)(out + (size_t)node * DIM + c0) = ov;
            }
        }
    }
}

// ---------------- per-node attention + aggregation (1 wave / node, fp16, 16B V loads) --------
// Score layout: lane = 4*jl + h (16 edges x 4 heads), K row 256B = 4 lanes x 4 x 16B.
// V layout: lane owns dims d16*8..+7 (d16 = lane&15, head hv = d16>>2); per 16-edge chunk,
//   4 passes of 4 edges (edge j = p*4 + lane>>4), one 16B half8 V load per lane per pass
//   -> 16 V loads/edge-chunk-lane-group vs 32 with 8B loads. Packed half2 accumulation;
//   cross-group combine via shfl_xor(16,32) at the end.
__global__ __launch_bounds__(256)
void attn_agg(const half_t* __restrict__ Qh, const half_t* __restrict__ Kh,
              const half_t* __restrict__ Vh, const int* __restrict__ offs,
              const int* __restrict__ srcs, half_t* __restrict__ AGG)
{
    const int lane = threadIdx.x & 63;
    const int t = blockIdx.x * 4 + (threadIdx.x >> 6);
    if (t >= N_NODES) return;
    const int off = offs[t];
    const int deg = offs[t + 1] - off;
    const int h   = lane & 3;
    const int jl  = lane >> 2;
    const int d16 = lane & 15;          // V dim-chunk (8 halves = 16B)
    const int hv  = d16 >> 2;           // head owning dims d16*8..+7
    const int jv  = lane >> 4;          // edge offset within a V pass

    half2_t q2[16];
    {
        const half_t* qp = Qh + (size_t)t * DIM + h * DH;
        #pragma unroll
        for (int i = 0; i < 4; ++i) {
            union { half8_t v8; half2_t v2[4]; } u;
            u.v8 = *(const half8_t*)(qp + i * 8);
            #pragma unroll
            for (int p = 0; p < 4; ++p) q2[i * 4 + p] = u.v2[p];
        }
    }

    float ssumL = 0.f;                       // per-lane (score layout)
    half2_t acc[4];                          // packed accum for dims d16*8..+7
    #pragma unroll
    for (int q = 0; q < 4; ++q) acc[q] = (half2_t)(_Float16)0.0f;
    const int nch = (deg + 15) >> 4;

    int sA = 0;
    half2_t kA[16] = {};
    {
        const int cnt0 = deg < 16 ? deg : 16;
        if (jl < cnt0) {
            sA = srcs[off + jl];
            const half_t* kp = Kh + (size_t)sA * DIM + h * DH;
            #pragma unroll
            for (int i = 0; i < 4; ++i) {
                union { half8_t v8; half2_t v2[4]; } u;
                u.v8 = *(const half8_t*)(kp + i * 8);
                #pragma unroll
                for (int p = 0; p < 4; ++p) kA[i * 4 + p] = u.v2[p];
            }
        }
    }

    for (int c = 0; c < nch; ++c) {
        const int base = c << 4;
        const int cnt = (deg - base) < 16 ? (deg - base) : 16;

        // prefetch next chunk's srcs + K
        int sB = 0;
        half2_t kB[16] = {};
        if (c + 1 < nch) {
            const int rem = deg - base - 16;
            const int cntn = rem < 16 ? rem : 16;
            if (jl < cntn) {
                sB = srcs[off + base + 16 + jl];
                const half_t* kp = Kh + (size_t)sB * DIM + h * DH;
                #pragma unroll
                for (int i = 0; i < 4; ++i) {
                    union { half8_t v8; half2_t v2[4]; } u;
                    u.v8 = *(const half8_t*)(kp + i * 8);
                    #pragma unroll
                    for (int p = 0; p < 4; ++p) kB[i * 4 + p] = u.v2[p];
                }
            }
        }

        // score for this lane's (edge jl, head h): packed fp16 dot
        float dq = 0.f;
        #pragma unroll
        for (int p = 0; p < 16; ++p)
            dq = __builtin_amdgcn_fdot2(kA[p], q2[p], dq, false);
        const float e = (jl < cnt) ? __expf(dq * SCALEF) : 0.f;
        ssumL += e;

        // packed (e,e) for broadcast
        union { u32 u; half2_t h2; } pe;
        const _Float16 eh = (_Float16)e;
        pe.h2[0] = eh; pe.h2[1] = eh;
        const int peI = (int)pe.u;

        // V aggregation: 4 passes x 4 edges; one 16B load per lane per pass
        #pragma unroll
        for (int p = 0; p < 4; ++p) {
            const int j  = p * 4 + jv;
            const int sj = __shfl(sA, j * 4);
            union { u32 u; half2_t h2; } e2;
            e2.u = (u32)__shfl(peI, j * 4 + hv);
            union { half8_t v8; half2_t h2[4]; } v;
            v.v8 = *(const half8_t*)(Vh + (size_t)sj * DIM + d16 * 8);
            acc[0] = e2.h2 * v.h2[0] + acc[0];
            acc[1] = e2.h2 * v.h2[1] + acc[1];
            acc[2] = e2.h2 * v.h2[2] + acc[2];
            acc[3] = e2.h2 * v.h2[3] + acc[3];
        }

        sA = sB;
        #pragma unroll
        for (int p = 0; p < 16; ++p) kA[p] = kB[p];
    }

    // combine the 4 edge groups (lanes l, l^16, l^32, l^48 hold the same dims)
    #pragma unroll
    for (int q = 0; q < 4; ++q) {
        union { u32 u; half2_t h2; } cq, dq16, dq32;
        cq.h2 = acc[q];
        dq16.u = (u32)__shfl_xor((int)cq.u, 16);
        cq.h2 = cq.h2 + dq16.h2;
        dq32.u = (u32)__shfl_xor((int)cq.u, 32);
        acc[q] = cq.h2 + dq32.h2;
    }

    // denominator: reduce ssumL over bits 2..5 (lanes sharing h); head-hv sum lives in lane hv
    float se = ssumL;
    #pragma unroll
    for (int ww = 4; ww < 64; ww <<= 1) se += __shfl_xor(se, ww);
    const float sh = __shfl(se, hv);
    const float inv = 1.0f / (sh + 1e-10f);

    if (lane < 16) {
        half8_t o;
        #pragma unroll
        for (int q = 0; q < 4; ++q) {
            o[2*q]   = (_Float16)((float)acc[q][0] * inv);
            o[2*q+1] = (_Float16)((float)acc[q][1] * inv);
        }
        *(half8_t*)(AGG + (size_t)t * DIM + d16 * 8) = o;
    }
}

extern "C" void kernel_launch(void* const* d_in, const int* in_sizes, int n_in,
                              void* d_out, int out_size, void* d_ws, size_t ws_size,
                              hipStream_t stream)
{
    const float* X   = (const float*)d_in[0];
    const float* Wq  = (const float*)d_in[1];
    const float* bq  = (const float*)d_in[2];
    const float* Wk  = (const float*)d_in[3];
    const float* bk  = (const float*)d_in[4];
    const float* Wv  = (const float*)d_in[5];
    const float* bv  = (const float*)d_in[6];
    const float* Wo  = (const float*)d_in[7];
    const float* bo  = (const float*)d_in[8];
    const float* lng = (const float*)d_in[9];
    const float* lnb = (const float*)d_in[10];
    const int*   ei  = (const int*)d_in[11];
    float* out = (float*)d_out;

    const size_t ND = (size_t)N_NODES * DIM;   // 6.4M elems
    half_t* Qh   = (half_t*)d_ws;
    half_t* Kh   = Qh + ND;
    half_t* Vh   = Kh + ND;
    half_t* AGGh = Vh + ND;
    half_t* Wqh  = AGGh + ND;
    half_t* Wkh  = Wqh + DIM * DIM;
    half_t* Wvh  = Wkh + DIM * DIM;
    half_t* Woh  = Wvh + DIM * DIM;
    u32* BE   = (u32*)(Woh + DIM * DIM);
    int* OFFS = (int*)(BE + NE);
    int* SRCS = OFFS + N_NODES + 1;
    int* GCNT = SRCS + NE;
    int* GBASE = GCNT + 512;
    int* GCUR  = GBASE + 512;

    hipMemsetAsync(GCNT, 0, 512 * sizeof(int), stream);

    // weights -> fp16 + bucket histogram (one launch)
    prep_kernel<<<32 + EB, 256, 0, stream>>>(Wq, Wk, Wv, Wo, Wqh, Wkh, Wvh, Woh,
                                             ei + NE, GCNT);

    // bucket scan -> base/cursor
    bucket_scan<<<1, 512, 0, stream>>>(GCNT, GBASE, GCUR, OFFS);

    // bucket scatter + QKV projections (one launch; independent block ranges)
    const int gemmGrid = (N_NODES + 127) / 128;   // 391
    scat_qkv<<<EB + gemmGrid, 256, 0, stream>>>(ei, GCUR, BE,
                                                X, Wqh, Wkh, Wvh, bq, bk, bv,
                                                Qh, Kh, Vh);

    // per-bucket CSR finalize (LDS atomics only)
    csr_build<<<NBKT, 256, 0, stream>>>(BE, GBASE, OFFS, SRCS);

    // attention + aggregation
    attn_agg<<<(N_NODES + 3) / 4, 256, 0, stream>>>(Qh, Kh, Vh, OFFS, SRCS, AGGh);

    // output projection + residual + LayerNorm
    out_mfma_ln<<<gemmGrid, 256, 0, stream>>>(AGGh, Woh, bo, X, lng, lnb, out);
}